// Round 7
// baseline (459.175 us; speedup 1.0000x reference)
//
#include <hip/hip_runtime.h>
#include <hip/hip_bf16.h>

// Problem constants
#define NB    1024   // batch
#define SEQ   512    // max seq len
#define DIM   128    // embedding dim (D)
#define HID   128    // hidden (H)
#define NOPS  16     // OPS
#define FEAT  144    // H + OPS
#define BQ    4      // samples per workgroup
#define AST   144    // sample stride inside a slot (bf16): breaks pow-2 bank strides
#define XST   578    // x slot stride (bf16) = 289 dwords, odd mod 32 -> ~2-way frag reads
#define TKST  (SEQ + 16)   // token buffer stride: padded so tk read needs no clamp

typedef __bf16 bf16x8 __attribute__((ext_vector_type(8)));
typedef float  floatx4 __attribute__((ext_vector_type(4)));

// R6: activations via raw v_exp_f32 + v_rcp_f32 (~1 ulp).
// R7: bias folded into exp2 arg (single FMA per gate now - no split-K).
__device__ __forceinline__ float sig_a(float a, float ka) {
    const float kS = -1.4426950408889634f;   // -log2(e)
    return __builtin_amdgcn_rcpf(1.0f + __builtin_amdgcn_exp2f(__builtin_fmaf(kS, a, ka)));
}
__device__ __forceinline__ float tanh_a(float a, float ka) {
    const float kT = -2.8853900817779268f;   // -2 log2(e)
    return 2.0f * __builtin_amdgcn_rcpf(1.0f + __builtin_amdgcn_exp2f(__builtin_fmaf(kT, a, ka))) - 1.0f;
}
__device__ __forceinline__ float tanh_c(float x) {
    const float kT = -2.8853900817779268f;
    return 2.0f * __builtin_amdgcn_rcpf(1.0f + __builtin_amdgcn_exp2f(kT * x)) - 1.0f;
}

// LDS-only barrier: drains lgkmcnt, leaves global gathers in flight.
__device__ __forceinline__ void block_sync_lds() {
    asm volatile("s_waitcnt lgkmcnt(0)\n\ts_barrier" ::: "memory");
}

// R9 (this round): 4-WAVE RESHAPE to halve LDS-pipe occupancy (the measured
// bottleneck: 8 waves x 4 h-frag ds_read_b128 = 32 reads/step ~ 600cy of the
// 740cy step). A-fragment reads amortize over col-tiles per wave, so:
//   4 waves x 8 col-tiles (each wave owns units [w*32,w*32+32) x 4 gate types)
//   -> 16 h-reads/step, same 160 MFMAs/step. 1 wave/SIMD, ~420 VGPR
//   (weights 256). Each lane holds TWO states (sample=quad, units uA/uA+16).
// All fragment mappings (A,B,C/D, xbuf/hbuf layout, slot rotation = 4G+OFF,
// h parity by t&1) identical to the proven 8-wave kernel. xg single-buffered
// (8 tiles = 32 regs), rebuilt at OFF==3 from slot group 1-G (write/read
// disjoint; ordered by the step barrier). No split-K: 8 independent 4-deep
// chains, kt-outer issue (re-issue distance 8 MFMAs > MFMA latency).
// Staging: sample=wave, units lane/lane+64; tokens in LDS; e-pipe 4 deep x2.
__global__ __launch_bounds__(256, 1)
void lstm_fused(const int* __restrict__ tokens, const int* __restrict__ lengths,
                const float* __restrict__ onehot, const float* __restrict__ emb,
                const float* __restrict__ Wih, const float* __restrict__ Whh,
                const float* __restrict__ bih, const float* __restrict__ bhh,
                const float* __restrict__ h0, const float* __restrict__ c0,
                const float* __restrict__ linW, const float* __restrict__ linb,
                float* __restrict__ out)
{
    __shared__ __align__(16) __bf16 xbuf[8 * XST];        // 8 rotating x slots
    __shared__ __align__(16) __bf16 hbuf[2 * BQ * AST];   // h, parity by t&1
    __shared__ __align__(16) float  hlbuf[BQ * HID];
    __shared__ __align__(16) int    tkbuf[BQ * TKST];     // tokens (+16 pad/sample)

    const int tid  = threadIdx.x;
    const int wave = tid >> 6;     // 0..3
    const int lane = tid & 63;
    const int quad = lane >> 4;
    const int lrow = lane & 15;
    const int bid  = blockIdx.x;

    // ---- Weight B-fragments: 8 col-tiles (gt,ct) per wave, 4 kt each. ----
    // B-layout (16x16x32): lane holds B[k=quad*8+j][n=lrow].
    bf16x8 wfx[4][2][4], wfh[4][2][4];
#pragma unroll
    for (int gt = 0; gt < 4; ++gt) {
#pragma unroll
        for (int ct = 0; ct < 2; ++ct) {
            const int g = gt * 128 + wave * 32 + ct * 16 + lrow;
#pragma unroll
            for (int kt = 0; kt < 4; ++kt) {
                const float* sx = Wih + g * DIM + kt * 32 + quad * 8;
                const float* sh = Whh + g * HID + kt * 32 + quad * 8;
                float4 a = *(const float4*)(sx);
                float4 b = *(const float4*)(sx + 4);
                bf16x8 v;
                v[0] = (__bf16)a.x; v[1] = (__bf16)a.y; v[2] = (__bf16)a.z; v[3] = (__bf16)a.w;
                v[4] = (__bf16)b.x; v[5] = (__bf16)b.y; v[6] = (__bf16)b.z; v[7] = (__bf16)b.w;
                wfx[gt][ct][kt] = v;
                a = *(const float4*)(sh);
                b = *(const float4*)(sh + 4);
                v[0] = (__bf16)a.x; v[1] = (__bf16)a.y; v[2] = (__bf16)a.z; v[3] = (__bf16)a.w;
                v[4] = (__bf16)b.x; v[5] = (__bf16)b.y; v[6] = (__bf16)b.z; v[7] = (__bf16)b.w;
                wfh[gt][ct][kt] = v;
            }
        }
    }

    // ---- Per-lane state: sample = quad, units uA = wave*32+lrow, uB = +16 ----
    const int uA = wave * 32 + lrow;
    const int uB = uA + 16;
    int lenq = lengths[bid * BQ + quad]; if (lenq < 1) lenq = 1;
    const int tlast = lenq - 1;

    int Lmax = 0;
#pragma unroll
    for (int s2 = 0; s2 < BQ; ++s2) {
        int l2 = lengths[bid * BQ + s2]; if (l2 < 1) l2 = 1;
        Lmax = (l2 > Lmax) ? l2 : Lmax;
    }

    const float kS = -1.4426950408889634f;
    const float kT = -2.8853900817779268f;
    const float kA0 = kS * (bih[0 * 128 + uA] + bhh[0 * 128 + uA]);
    const float kA1 = kS * (bih[1 * 128 + uA] + bhh[1 * 128 + uA]);
    const float kA2 = kT * (bih[2 * 128 + uA] + bhh[2 * 128 + uA]);
    const float kA3 = kS * (bih[3 * 128 + uA] + bhh[3 * 128 + uA]);
    const float kB0 = kS * (bih[0 * 128 + uB] + bhh[0 * 128 + uB]);
    const float kB1 = kS * (bih[1 * 128 + uB] + bhh[1 * 128 + uB]);
    const float kB2 = kT * (bih[2 * 128 + uB] + bhh[2 * 128 + uB]);
    const float kB3 = kS * (bih[3 * 128 + uB] + bhh[3 * 128 + uB]);

    float cA = c0[uA], cB = c0[uB];
    float hlA = 0.0f, hlB = 0.0f;

    // ---- Staging mapping: sample = wave, units lane and lane+64 ----
    const int bm = bid * BQ + wave;
    const int* tokm = tokens + (size_t)bm * SEQ;

    // tokens -> LDS (2 int4 per thread); zero the 16-entry tail per sample
    {
        *(int4*)(&tkbuf[wave * TKST + lane * 8])     = *(const int4*)(tokm + lane * 8);
        *(int4*)(&tkbuf[wave * TKST + lane * 8 + 4]) = *(const int4*)(tokm + lane * 8 + 4);
        if (tid < BQ * 16)
            tkbuf[(tid >> 4) * TKST + SEQ + (tid & 15)] = 0;
    }

    hbuf[wave * AST + lane]      = (__bf16)h0[lane];
    hbuf[wave * AST + lane + 64] = (__bf16)h0[lane + 64];
#pragma unroll
    for (int k = 0; k < 8; ++k) {   // stage x(0..7) into slots 0..7
        const size_t row = (size_t)tokm[k] * DIM;
        xbuf[k * XST + wave * AST + lane]      = (__bf16)fmaxf(emb[row + lane], 0.0f);
        xbuf[k * XST + wave * AST + lane + 64] = (__bf16)fmaxf(emb[row + lane + 64], 0.0f);
    }
    // gather pipeline, 4 steps deep, two unit-halves per thread
    float eA0 = emb[(size_t)tokm[8]  * DIM + lane], eB0 = emb[(size_t)tokm[8]  * DIM + lane + 64];
    float eA1 = emb[(size_t)tokm[9]  * DIM + lane], eB1 = emb[(size_t)tokm[9]  * DIM + lane + 64];
    float eA2 = emb[(size_t)tokm[10] * DIM + lane], eB2 = emb[(size_t)tokm[10] * DIM + lane + 64];
    float eA3 = emb[(size_t)tokm[11] * DIM + lane], eB3 = emb[(size_t)tokm[11] * DIM + lane + 64];
    int   tk  = tokm[12];

#define EA(OFF) ((OFF) == 0 ? eA0 : (OFF) == 1 ? eA1 : (OFF) == 2 ? eA2 : eA3)
#define EB(OFF) ((OFF) == 0 ? eB0 : (OFF) == 1 ? eB1 : (OFF) == 2 ? eB2 : eB3)

    // frag pointers (layouts identical to the 8-wave kernel)
    const int xfbase = (lrow & 3) * XST + (lrow >> 2) * AST + quad * 8;
    const __bf16* const xfp[2] = { &xbuf[xfbase], &xbuf[4 * XST + xfbase] };
    const int habase = (lrow >> 2) * AST + quad * 8;
    const __bf16* const hf[2] = { &hbuf[habase], &hbuf[BQ * AST + habase] };
    __bf16* const hwA[2] = { &hbuf[quad * AST + uA], &hbuf[BQ * AST + quad * AST + uA] };
    __bf16* const hwB[2] = { &hbuf[quad * AST + uB], &hbuf[BQ * AST + quad * AST + uB] };
    __bf16* const xwA = &xbuf[wave * AST + lane];
    __bf16* const xwB = &xbuf[wave * AST + lane + 64];

    __syncthreads();   // x(0..7), h(0), tokens staged

    const floatx4 zc = {0.0f, 0.0f, 0.0f, 0.0f};

    // xg[gt][ct][r] = x(ts+r)@W_ih^T (no bias); built from slot group 0
    floatx4 xg[4][2];
    {
        bf16x8 af_[4];
#pragma unroll
        for (int kt = 0; kt < 4; ++kt)
            af_[kt] = *(const bf16x8*)(xfp[0] + kt * 32);
#pragma unroll
        for (int kt = 0; kt < 4; ++kt)
#pragma unroll
            for (int gt = 0; gt < 4; ++gt)
#pragma unroll
                for (int ct = 0; ct < 2; ++ct)
                    xg[gt][ct] = __builtin_amdgcn_mfma_f32_16x16x32_bf16(
                        af_[kt], wfx[gt][ct][kt], kt == 0 ? zc : xg[gt][ct], 0, 0, 0);
    }
    block_sync_lds();   // slots 0..3 rewritten starting at step 0 (x(8))

    // G, OFF literals. Per step: h-frag reads -> staging (in read shadow) ->
    // 8x4 kt-outer h-MFMA chains (C=xg at kt0) -> xg rebuild at OFF==3 from
    // group 1-G (disjoint from this superstep's writes to group G) ->
    // two activation chains -> 2 h-writes -> drain+barrier.
#define STEP(G, OFF) do {                                                            \
        const int t = ts + OFF;                                                      \
        bf16x8 ah_[4];                                                               \
        _Pragma("unroll") for (int kt = 0; kt < 4; ++kt)                             \
            ah_[kt] = *(const bf16x8*)(hf[OFF & 1] + kt * 32);                       \
        if (t + 8 < SEQ) {   /* stage x(t+8); slot = (t+8)&7 = 4G+OFF */             \
            xwA[(4 * (G) + (OFF)) * XST] = (__bf16)fmaxf(EA(OFF), 0.0f);             \
            xwB[(4 * (G) + (OFF)) * XST] = (__bf16)fmaxf(EB(OFF), 0.0f);             \
        }                                                                            \
        if (t + 12 < SEQ) {  /* gather for x(t+12) */                                \
            const size_t row = (size_t)tk * DIM;                                     \
            EA(OFF) = emb[row + lane];                                               \
            EB(OFF) = emb[row + lane + 64];                                          \
        }                                                                            \
        tk = tkbuf[wave * TKST + t + 13];                                            \
        floatx4 acc[4][2];                                                           \
        _Pragma("unroll") for (int kt = 0; kt < 4; ++kt)                             \
            _Pragma("unroll") for (int gt = 0; gt < 4; ++gt)                         \
                _Pragma("unroll") for (int ct = 0; ct < 2; ++ct)                     \
                    acc[gt][ct] = __builtin_amdgcn_mfma_f32_16x16x32_bf16(           \
                        ah_[kt], wfh[gt][ct][kt], kt == 0 ? xg[gt][ct] : acc[gt][ct], 0, 0, 0); \
        if (OFF == 3 && ts + 4 < Lmax) {   /* rebuild xg from group 1-G */           \
            bf16x8 af_[4];                                                           \
            _Pragma("unroll") for (int kt = 0; kt < 4; ++kt)                         \
                af_[kt] = *(const bf16x8*)(xfp[1 - (G)] + kt * 32);                  \
            _Pragma("unroll") for (int kt = 0; kt < 4; ++kt)                         \
                _Pragma("unroll") for (int gt = 0; gt < 4; ++gt)                     \
                    _Pragma("unroll") for (int ct = 0; ct < 2; ++ct)                 \
                        xg[gt][ct] = __builtin_amdgcn_mfma_f32_16x16x32_bf16(        \
                            af_[kt], wfx[gt][ct][kt], kt == 0 ? zc : xg[gt][ct], 0, 0, 0); \
        }                                                                            \
        const float iA = sig_a (acc[0][0][OFF], kA0);                                \
        const float fA = sig_a (acc[1][0][OFF], kA1);                                \
        const float gA = tanh_a(acc[2][0][OFF], kA2);                                \
        const float oA = sig_a (acc[3][0][OFF], kA3);                                \
        const float iB = sig_a (acc[0][1][OFF], kB0);                                \
        const float fB = sig_a (acc[1][1][OFF], kB1);                                \
        const float gB = tanh_a(acc[2][1][OFF], kB2);                                \
        const float oB = sig_a (acc[3][1][OFF], kB3);                                \
        cA = fA * cA + iA * gA;                                                      \
        cB = fB * cB + iB * gB;                                                      \
        const float hA = oA * tanh_c(cA);                                            \
        const float hB = oB * tanh_c(cB);                                            \
        if (t == tlast) { hlA = fmaxf(hA, 0.0f); hlB = fmaxf(hB, 0.0f); }            \
        *hwA[1 - (OFF & 1)] = (__bf16)hA;                                            \
        *hwB[1 - (OFF & 1)] = (__bf16)hB;                                            \
        block_sync_lds();                                                            \
    } while (0)

    for (int ts8 = 0; ts8 < Lmax; ts8 += 8) {
        {
            const int ts = ts8;
            STEP(0, 0); STEP(0, 1); STEP(0, 2); STEP(0, 3);
        }
        {
            const int ts = ts8 + 4;
            STEP(1, 0); STEP(1, 1); STEP(1, 2); STEP(1, 3);
        }
    }
#undef STEP
#undef EA
#undef EB

    // ---- epilogue: out[b] = [relu(h_last) | onehot] @ linW^T + linb ----
    hlbuf[quad * HID + uA] = hlA;
    hlbuf[quad * HID + uB] = hlB;
    __syncthreads();
    if (tid < 2 * BQ) {
        const int mm = tid >> 1, kk = tid & 1;
        const int bb = bid * BQ + mm;
        float a2 = linb[kk];
        for (int q = 0; q < HID; ++q)
            a2 += hlbuf[mm * HID + q] * linW[kk * FEAT + q];
        for (int o = 0; o < NOPS; ++o)
            a2 += onehot[bb * NOPS + o] * linW[kk * FEAT + HID + o];
        out[bb * 2 + kk] = a2;
    }
}

extern "C" void kernel_launch(void* const* d_in, const int* in_sizes, int n_in,
                              void* d_out, int out_size, void* d_ws, size_t ws_size,
                              hipStream_t stream) {
    const int*   tokens  = (const int*)d_in[0];
    const int*   lengths = (const int*)d_in[1];
    const float* onehot  = (const float*)d_in[2];
    const float* emb     = (const float*)d_in[3];
    const float* Wih     = (const float*)d_in[4];
    const float* Whh     = (const float*)d_in[5];
    const float* bih     = (const float*)d_in[6];
    const float* bhh     = (const float*)d_in[7];
    const float* h0      = (const float*)d_in[8];
    const float* c0      = (const float*)d_in[9];
    const float* linW    = (const float*)d_in[10];
    const float* linb    = (const float*)d_in[11];
    float* out = (float*)d_out;
    (void)in_sizes; (void)n_in; (void)out_size; (void)d_ws; (void)ws_size;

    lstm_fused<<<dim3(NB / BQ), dim3(256), 0, stream>>>(
        tokens, lengths, onehot, emb, Wih, Whh, bih, bhh, h0, c0, linW, linb, out);
}

// Round 11
// 417.419 us; speedup vs baseline: 1.1000x; 1.1000x over previous
//
#include <hip/hip_runtime.h>
#include <hip/hip_bf16.h>

// Problem constants
#define NB    1024   // batch
#define SEQ   512    // max seq len
#define DIM   128    // embedding dim (D)
#define HID   128    // hidden (H)
#define NOPS  16     // OPS
#define FEAT  144    // H + OPS
#define BQ    4      // samples per workgroup
#define AST   144    // sample stride inside a slot (bf16): breaks pow-2 bank strides
#define XST   578    // x slot stride (bf16) = 289 dwords, odd mod 32 -> ~2-way frag reads
#define TKST  (SEQ + 16)   // token buffer stride: padded so tk read needs no clamp

typedef __bf16 bf16x8 __attribute__((ext_vector_type(8)));
typedef float  floatx4 __attribute__((ext_vector_type(4)));

// R6: activations via raw v_exp_f32 + v_rcp_f32 (~1 ulp, invisible at absmax).
// R7: bias folded into the exp2 argument (2 FMAs replace add+add+mul).
__device__ __forceinline__ float gate_s(float aL, float aH, float ka) {
    const float kS = -1.4426950408889634f;   // -log2(e)
    const float arg = __builtin_fmaf(kS, aL, __builtin_fmaf(kS, aH, ka));
    return __builtin_amdgcn_rcpf(1.0f + __builtin_amdgcn_exp2f(arg));
}

// LDS-only barrier: drains lgkmcnt (all cross-wave traffic is LDS), leaves
// global gathers in flight.
__device__ __forceinline__ void block_sync_lds() {
    asm volatile("s_waitcnt lgkmcnt(0)\n\ts_barrier" ::: "memory");
}

// One WG = 512 threads (8 waves) owns BQ=4 samples. Wave w owns unit-chunk w
// for all 4 gate types. 4-STEP X-PACKING: x-gates for 4 samples x 4 timesteps
// per superstep (per-step kt-slice accumulation into XGN); in-loop serial
// MFMAs are h-part only, split-K 2-deep, fed C=xg. Tokens staged to LDS once;
// emb gathers 4 steps deep.
//
// R10: fill the post-barrier h-read latency window. LDS returns in-order, so
// anything queued behind the h-reads stalls with them.
//   (a) x-slice frag (ax_) PREFETCHED PRE-BARRIER for OFF=1..3 (group 1-G is
//       stable all superstep; only the OFF==0 step -- whose group was written
//       in the previous barrier interval -- must load post-barrier). The 4
//       x-MFMAs then issue during the h-read wait with in-register operands.
//   (b) tk read moved pre-barrier (tkbuf static -> always safe).
//   (c) act chain re-associated: i*tanh(g) = fma(2i,rg,-i), h = o*tanh(c) =
//       fma(2o,rc,-o): one dependent level removed after each rcp.
// R9 lesson (reverted): 4-wave/8-col-tile reshape hits the 256 arch-VGPR
// ceiling (64 weight frags = 256 VGPR) and spills per-loop (WRITE_SIZE 2x).
// h A-frag reads are 4-way same-address replicated (LDS broadcast) -- the
// LDS pipe is NOT the bottleneck; the lockstep-exposed latency chain is.
__global__ __launch_bounds__(512, 2)
void lstm_fused(const int* __restrict__ tokens, const int* __restrict__ lengths,
                const float* __restrict__ onehot, const float* __restrict__ emb,
                const float* __restrict__ Wih, const float* __restrict__ Whh,
                const float* __restrict__ bih, const float* __restrict__ bhh,
                const float* __restrict__ h0, const float* __restrict__ c0,
                const float* __restrict__ linW, const float* __restrict__ linb,
                float* __restrict__ out)
{
    __shared__ __align__(16) __bf16 xbuf[8 * XST];        // 8 rotating x slots
    __shared__ __align__(16) __bf16 hbuf[2 * BQ * AST];   // h, parity by t&1
    __shared__ __align__(16) float  hlbuf[BQ * HID];
    __shared__ __align__(16) int    tkbuf[BQ * TKST];     // tokens (+16 pad/sample)

    const int tid  = threadIdx.x;
    const int wave = tid >> 6;
    const int lane = tid & 63;
    const int quad = lane >> 4;
    const int lrow = lane & 15;
    const int bid  = blockIdx.x;

    // ---- Weight B-fragments in registers (loaded once). ----
    // B-layout (16x16x32): lane holds B[k=quad*8+j][n=lrow].
    bf16x8 wfx[4][4], wfh[4][4];
#pragma unroll
    for (int gt = 0; gt < 4; ++gt) {
        const int g = gt * 128 + wave * 16 + lrow;
#pragma unroll
        for (int kt = 0; kt < 4; ++kt) {
            const float* sx = Wih + g * DIM + kt * 32 + quad * 8;
            const float* sh = Whh + g * HID + kt * 32 + quad * 8;
            float4 a = *(const float4*)(sx);
            float4 b = *(const float4*)(sx + 4);
            bf16x8 v;
            v[0] = (__bf16)a.x; v[1] = (__bf16)a.y; v[2] = (__bf16)a.z; v[3] = (__bf16)a.w;
            v[4] = (__bf16)b.x; v[5] = (__bf16)b.y; v[6] = (__bf16)b.z; v[7] = (__bf16)b.w;
            wfx[gt][kt] = v;
            a = *(const float4*)(sh);
            b = *(const float4*)(sh + 4);
            v[0] = (__bf16)a.x; v[1] = (__bf16)a.y; v[2] = (__bf16)a.z; v[3] = (__bf16)a.w;
            v[4] = (__bf16)b.x; v[5] = (__bf16)b.y; v[6] = (__bf16)b.z; v[7] = (__bf16)b.w;
            wfh[gt][kt] = v;
        }
    }

    // ---- Per-lane state: sample = quad, unit = uu = wave*16 + lrow ----
    const int uu = wave * 16 + lrow;
    const int bq = bid * BQ + quad;
    int lenq = lengths[bq]; if (lenq < 1) lenq = 1;
    const int tlast = lenq - 1;

    int Lmax = 0;
#pragma unroll
    for (int s2 = 0; s2 < BQ; ++s2) {
        int l2 = lengths[bid * BQ + s2]; if (l2 < 1) l2 = 1;
        Lmax = (l2 > Lmax) ? l2 : Lmax;
    }

    // per-gate activation-arg constants: karg = k * (bih + bhh)
    const float kS = -1.4426950408889634f;
    const float kT = -2.8853900817779268f;
    const float karg0 = kS * (bih[0 * 128 + uu] + bhh[0 * 128 + uu]);
    const float karg1 = kS * (bih[1 * 128 + uu] + bhh[1 * 128 + uu]);
    const float karg2 = kT * (bih[2 * 128 + uu] + bhh[2 * 128 + uu]);
    const float karg3 = kS * (bih[3 * 128 + uu] + bhh[3 * 128 + uu]);

    float c  = c0[uu];
    float hl = 0.0f;

    // ---- Staging thread layout: m = tid>>7 (sample), u = tid&127 (unit) ----
    const int m  = tid >> 7;
    const int u  = tid & 127;
    const int bm = bid * BQ + m;
    const int sm = m * AST + u;

    // Stage ALL tokens for this WG's 4 samples into LDS (one int4 / thread,
    // coalesced src). Padded stride; zero-fill the 16-entry tail.
    {
        const int4 tv = *(const int4*)(tokens + (size_t)bm * SEQ + (tid & 127) * 4);
        *(int4*)(&tkbuf[m * TKST + (tid & 127) * 4]) = tv;
        if (tid < BQ * 16)
            tkbuf[(tid >> 4) * TKST + SEQ + (tid & 15)] = 0;
    }

    hbuf[sm] = (__bf16)h0[u];
    const int* tokm = tokens + (size_t)bm * SEQ;
#pragma unroll
    for (int k = 0; k < 8; ++k) {   // stage x(0..7) into slots 0..7
        float ek = emb[(size_t)tokm[k] * DIM + u];
        xbuf[k * XST + sm] = (__bf16)fmaxf(ek, 0.0f);
    }
    // gather pipeline, 4 steps deep (one reg per OFF): e(OFF) written at step
    // t (as x(t+8)) then reloaded for step t+4 (as x(t+12)). tk = token for
    // the step-0 reload (x(12)), read one step ahead.
    float e0 = emb[(size_t)tokm[8]  * DIM + u];
    float e1 = emb[(size_t)tokm[9]  * DIM + u];
    float e2 = emb[(size_t)tokm[10] * DIM + u];
    float e3 = emb[(size_t)tokm[11] * DIM + u];
    int   tk = tokm[12];

#define EREG(OFF) ((OFF) == 0 ? e0 : (OFF) == 1 ? e1 : (OFF) == 2 ? e2 : e3)

    // frag pointers
    const int xfbase = (lrow & 3) * XST + (lrow >> 2) * AST + quad * 8;
    const __bf16* const xfp[2] = { &xbuf[xfbase], &xbuf[4 * XST + xfbase] };
    const int habase = (lrow >> 2) * AST + quad * 8;
    const __bf16* const hf[2] = { &hbuf[habase], &hbuf[BQ * AST + habase] };
    __bf16* const hw[2] = { &hbuf[quad * AST + uu], &hbuf[BQ * AST + quad * AST + uu] };
    __bf16* const xw = &xbuf[sm];

    __syncthreads();   // x(0..7), h(0), tokens staged

    const floatx4 zc = {0.0f, 0.0f, 0.0f, 0.0f};   // zero C-init

    // XG[gt][r] = x(ts'+r)@W_ih^T (no bias) for (sample quad, unit uu).
    // xga for superstep 0 built in full here (from slots 0..3); thereafter
    // XGN accumulates one kt-slice per step inside STEP.
    floatx4 xga[4], xgb[4];
    {
        bf16x8 af_[4];
#pragma unroll
        for (int kt = 0; kt < 4; ++kt)
            af_[kt] = *(const bf16x8*)(xfp[0] + kt * 32);
#pragma unroll
        for (int gt = 0; gt < 4; ++gt)
            xga[gt] = __builtin_amdgcn_mfma_f32_16x16x32_bf16(af_[0], wfx[gt][0], zc, 0, 0, 0);
#pragma unroll
        for (int kt = 1; kt < 4; ++kt)
#pragma unroll
            for (int gt = 0; gt < 4; ++gt)
                xga[gt] = __builtin_amdgcn_mfma_f32_16x16x32_bf16(af_[kt], wfx[gt][kt], xga[gt], 0, 0, 0);
    }
    block_sync_lds();    // slots 0..3 rewritten starting at step 0 (x(8))

    bf16x8 axp = {};     // pre-barrier-prefetched x-slice frag (OFF=1..3)

    // G, OFF literals. Per-step order:
    //   post-barrier: 4 h-frag reads (only LDS ops in the in-order queue);
    //   ax_ = axp (in-register, OFF>0) or fresh load (OFF==0);
    //   staging (x-write + gather issue) in the h-read shadow;
    //   x-slice MFMAs first for OFF>0 (operands ready -> issue during h-wait)
    //   then split-K h-MFMA (2x2-deep, C=XGC, XGC preserved since D!=C);
    //   re-associated activations; h-write;
    //   pre-barrier: axp prefetch (OFF<3) + tk read; minimal drain + barrier.
#define STEP(G, OFF, XGC, XGN) do {                                                  \
        const int t  = ts + OFF;                                                     \
        bf16x8 ah0 = *(const bf16x8*)(hf[OFF & 1] + 0 * 32);                         \
        bf16x8 ah2 = *(const bf16x8*)(hf[OFF & 1] + 2 * 32);                         \
        bf16x8 ah1 = *(const bf16x8*)(hf[OFF & 1] + 1 * 32);                         \
        bf16x8 ah3 = *(const bf16x8*)(hf[OFF & 1] + 3 * 32);                         \
        bf16x8 ax_;                                                                  \
        if ((OFF) == 0) ax_ = *(const bf16x8*)(xfp[1 - (G)] + 0 * 32);               \
        else            ax_ = axp;                                                   \
        if (t + 8 < SEQ)   /* stage x(t+8) from the reg gathered 4 steps ago */      \
            xw[(4 * (G) + (OFF)) * XST] = (__bf16)fmaxf(EREG(OFF), 0.0f);            \
        if (t + 12 < SEQ)  /* gather for x(t+12) */                                  \
            EREG(OFF) = emb[(size_t)tk * DIM + u];                                   \
        floatx4 aL[4], aH[4];                                                        \
        if ((OFF) != 0) {  /* x-MFMAs first: operands ready, fill h-read wait */     \
            _Pragma("unroll") for (int gt = 0; gt < 4; ++gt)                         \
                XGN[gt] = __builtin_amdgcn_mfma_f32_16x16x32_bf16(ax_, wfx[gt][OFF], XGN[gt], 0, 0, 0); \
        }                                                                            \
        _Pragma("unroll") for (int gt = 0; gt < 4; ++gt)                             \
            aL[gt] = __builtin_amdgcn_mfma_f32_16x16x32_bf16(ah0, wfh[gt][0], XGC[gt], 0, 0, 0); \
        _Pragma("unroll") for (int gt = 0; gt < 4; ++gt)                             \
            aH[gt] = __builtin_amdgcn_mfma_f32_16x16x32_bf16(ah2, wfh[gt][2], zc, 0, 0, 0); \
        _Pragma("unroll") for (int gt = 0; gt < 4; ++gt)                             \
            aL[gt] = __builtin_amdgcn_mfma_f32_16x16x32_bf16(ah1, wfh[gt][1], aL[gt], 0, 0, 0); \
        _Pragma("unroll") for (int gt = 0; gt < 4; ++gt)                             \
            aH[gt] = __builtin_amdgcn_mfma_f32_16x16x32_bf16(ah3, wfh[gt][3], aH[gt], 0, 0, 0); \
        if ((OFF) == 0) {  /* ax_ loaded post-barrier: issue after h-MFMAs */        \
            _Pragma("unroll") for (int gt = 0; gt < 4; ++gt)                         \
                XGN[gt] = __builtin_amdgcn_mfma_f32_16x16x32_bf16(ax_, wfx[gt][0], zc, 0, 0, 0); \
        }                                                                            \
        const float ii = gate_s(aL[0][OFF], aH[0][OFF], karg0);                      \
        const float ff = gate_s(aL[1][OFF], aH[1][OFF], karg1);                      \
        const float oo = gate_s(aL[3][OFF], aH[3][OFF], karg3);                      \
        const float rg = __builtin_amdgcn_rcpf(1.0f + __builtin_amdgcn_exp2f(       \
            __builtin_fmaf(kT, aL[2][OFF], __builtin_fmaf(kT, aH[2][OFF], karg2)))); \
        const float ig = __builtin_fmaf(2.0f * ii, rg, -ii);  /* i*tanh(g) */        \
        c = __builtin_fmaf(ff, c, ig);                                               \
        const float rc = __builtin_amdgcn_rcpf(1.0f + __builtin_amdgcn_exp2f(kT * c)); \
        const float h = __builtin_fmaf(2.0f * oo, rc, -oo);   /* o*tanh(c) */        \
        if (t == tlast) hl = fmaxf(h, 0.0f);                                         \
        *hw[1 - (OFF & 1)] = (__bf16)h;                                              \
        if ((OFF) < 3)     /* prefetch next step's x-slice (group 1-G stable) */     \
            axp = *(const bf16x8*)(xfp[1 - (G)] + ((OFF) + 1) * 32);                 \
        tk = tkbuf[m * TKST + t + 13];                                               \
        block_sync_lds();                                                            \
    } while (0)

    for (int ts8 = 0; ts8 < Lmax; ts8 += 8) {
        {
            const int ts = ts8;
            STEP(0, 0, xga, xgb); STEP(0, 1, xga, xgb);
            STEP(0, 2, xga, xgb); STEP(0, 3, xga, xgb);
        }
        {
            const int ts = ts8 + 4;
            STEP(1, 0, xgb, xga); STEP(1, 1, xgb, xga);
            STEP(1, 2, xgb, xga); STEP(1, 3, xgb, xga);
        }
    }
#undef STEP
#undef EREG

    // ---- epilogue: out[b] = [relu(h_last) | onehot] @ linW^T + linb ----
    hlbuf[quad * HID + uu] = hl;
    __syncthreads();
    if (tid < 2 * BQ) {
        const int mm = tid >> 1, kk = tid & 1;
        const int bb = bid * BQ + mm;
        float a2 = linb[kk];
        for (int q = 0; q < HID; ++q)
            a2 += hlbuf[mm * HID + q] * linW[kk * FEAT + q];
        for (int o = 0; o < NOPS; ++o)
            a2 += onehot[bb * NOPS + o] * linW[kk * FEAT + HID + o];
        out[bb * 2 + kk] = a2;
    }
}

extern "C" void kernel_launch(void* const* d_in, const int* in_sizes, int n_in,
                              void* d_out, int out_size, void* d_ws, size_t ws_size,
                              hipStream_t stream) {
    const int*   tokens  = (const int*)d_in[0];
    const int*   lengths = (const int*)d_in[1];
    const float* onehot  = (const float*)d_in[2];
    const float* emb     = (const float*)d_in[3];
    const float* Wih     = (const float*)d_in[4];
    const float* Whh     = (const float*)d_in[5];
    const float* bih     = (const float*)d_in[6];
    const float* bhh     = (const float*)d_in[7];
    const float* h0      = (const float*)d_in[8];
    const float* c0      = (const float*)d_in[9];
    const float* linW    = (const float*)d_in[10];
    const float* linb    = (const float*)d_in[11];
    float* out = (float*)d_out;
    (void)in_sizes; (void)n_in; (void)out_size; (void)d_ws; (void)ws_size;

    lstm_fused<<<dim3(NB / BQ), dim3(512), 0, stream>>>(
        tokens, lengths, onehot, emb, Wih, Whh, bih, bhh, h0, c0, linW, linb, out);
}

// Round 12
// 410.733 us; speedup vs baseline: 1.1179x; 1.0163x over previous
//
#include <hip/hip_runtime.h>
#include <hip/hip_bf16.h>

// Problem constants
#define NB    1024   // batch
#define SEQ   512    // max seq len
#define DIM   128    // embedding dim (D)
#define HID   128    // hidden (H)
#define NOPS  16     // OPS
#define FEAT  144    // H + OPS
#define BQ    4      // samples per workgroup
#define AST   144    // sample stride inside a slot (bf16): breaks pow-2 bank strides
#define XST   578    // x slot stride (bf16) = 289 dwords, odd mod 32 -> ~2-way frag reads
#define TKST  (SEQ + 16)   // token buffer stride: padded so tk read needs no clamp

typedef __bf16 bf16x8 __attribute__((ext_vector_type(8)));
typedef float  floatx4 __attribute__((ext_vector_type(4)));

// R6: activations via raw v_exp_f32 + v_rcp_f32 (~1 ulp, invisible at absmax).
// R7: bias folded into the exp2 argument (2 FMAs replace add+add+mul).
__device__ __forceinline__ float gate_s(float aL, float aH, float ka) {
    const float kS = -1.4426950408889634f;   // -log2(e)
    const float arg = __builtin_fmaf(kS, aL, __builtin_fmaf(kS, aH, ka));
    return __builtin_amdgcn_rcpf(1.0f + __builtin_amdgcn_exp2f(arg));
}

// LDS-only barrier: drains lgkmcnt (all cross-wave traffic is LDS), leaves
// global gathers in flight.
__device__ __forceinline__ void block_sync_lds() {
    asm volatile("s_waitcnt lgkmcnt(0)\n\ts_barrier" ::: "memory");
}

// One WG = 512 threads (8 waves) owns BQ=4 samples. Wave w owns unit-chunk w
// for all 4 gate types. 4-STEP X-PACKING: x-gates for 4 samples x 4 timesteps
// per superstep (per-step kt-slice accumulation into XGN); in-loop serial
// MFMAs are h-part only, split-K 2-deep, fed C=xg. Tokens staged to LDS once;
// emb gathers 4 steps deep.
//
// R11 (this round): LDS-latency placement fix. LDS retirement is IN-ORDER,
// so the R10 placement of the axp/tk ds_reads immediately before the
// lgkmcnt(0)+s_barrier serialized their full ~120cy latency into every
// step's barrier drain (~100-130 of the 236cy/step residual stall). Moving
// both reads to the TOP of the step (staging section) absorbs their latency
// under the ~300cy MFMA+activation phase; the end-of-step drain then covers
// only the h-write commit. Old values are consumed before the reloads
// (gather uses old tk, x-MFMA uses old axp -- SSA, no hazard).
// R10 (kept): axp pre-loaded so x-MFMAs issue with in-register operands in
// the post-barrier h-read wait; act chain re-associated (fma(2i,rg,-i) etc).
// R9 lesson (reverted): 4-wave/8-col-tile reshape hits the 256 arch-VGPR
// ceiling and spills per-loop. The lockstep-exposed latency chain, not the
// LDS pipe, is the bottleneck.
__global__ __launch_bounds__(512, 2)
void lstm_fused(const int* __restrict__ tokens, const int* __restrict__ lengths,
                const float* __restrict__ onehot, const float* __restrict__ emb,
                const float* __restrict__ Wih, const float* __restrict__ Whh,
                const float* __restrict__ bih, const float* __restrict__ bhh,
                const float* __restrict__ h0, const float* __restrict__ c0,
                const float* __restrict__ linW, const float* __restrict__ linb,
                float* __restrict__ out)
{
    __shared__ __align__(16) __bf16 xbuf[8 * XST];        // 8 rotating x slots
    __shared__ __align__(16) __bf16 hbuf[2 * BQ * AST];   // h, parity by t&1
    __shared__ __align__(16) float  hlbuf[BQ * HID];
    __shared__ __align__(16) int    tkbuf[BQ * TKST];     // tokens (+16 pad/sample)

    const int tid  = threadIdx.x;
    const int wave = tid >> 6;
    const int lane = tid & 63;
    const int quad = lane >> 4;
    const int lrow = lane & 15;
    const int bid  = blockIdx.x;

    // ---- Weight B-fragments in registers (loaded once). ----
    // B-layout (16x16x32): lane holds B[k=quad*8+j][n=lrow].
    bf16x8 wfx[4][4], wfh[4][4];
#pragma unroll
    for (int gt = 0; gt < 4; ++gt) {
        const int g = gt * 128 + wave * 16 + lrow;
#pragma unroll
        for (int kt = 0; kt < 4; ++kt) {
            const float* sx = Wih + g * DIM + kt * 32 + quad * 8;
            const float* sh = Whh + g * HID + kt * 32 + quad * 8;
            float4 a = *(const float4*)(sx);
            float4 b = *(const float4*)(sx + 4);
            bf16x8 v;
            v[0] = (__bf16)a.x; v[1] = (__bf16)a.y; v[2] = (__bf16)a.z; v[3] = (__bf16)a.w;
            v[4] = (__bf16)b.x; v[5] = (__bf16)b.y; v[6] = (__bf16)b.z; v[7] = (__bf16)b.w;
            wfx[gt][kt] = v;
            a = *(const float4*)(sh);
            b = *(const float4*)(sh + 4);
            v[0] = (__bf16)a.x; v[1] = (__bf16)a.y; v[2] = (__bf16)a.z; v[3] = (__bf16)a.w;
            v[4] = (__bf16)b.x; v[5] = (__bf16)b.y; v[6] = (__bf16)b.z; v[7] = (__bf16)b.w;
            wfh[gt][kt] = v;
        }
    }

    // ---- Per-lane state: sample = quad, unit = uu = wave*16 + lrow ----
    const int uu = wave * 16 + lrow;
    const int bq = bid * BQ + quad;
    int lenq = lengths[bq]; if (lenq < 1) lenq = 1;
    const int tlast = lenq - 1;

    int Lmax = 0;
#pragma unroll
    for (int s2 = 0; s2 < BQ; ++s2) {
        int l2 = lengths[bid * BQ + s2]; if (l2 < 1) l2 = 1;
        Lmax = (l2 > Lmax) ? l2 : Lmax;
    }

    // per-gate activation-arg constants: karg = k * (bih + bhh)
    const float kS = -1.4426950408889634f;
    const float kT = -2.8853900817779268f;
    const float karg0 = kS * (bih[0 * 128 + uu] + bhh[0 * 128 + uu]);
    const float karg1 = kS * (bih[1 * 128 + uu] + bhh[1 * 128 + uu]);
    const float karg2 = kT * (bih[2 * 128 + uu] + bhh[2 * 128 + uu]);
    const float karg3 = kS * (bih[3 * 128 + uu] + bhh[3 * 128 + uu]);

    float c  = c0[uu];
    float hl = 0.0f;

    // ---- Staging thread layout: m = tid>>7 (sample), u = tid&127 (unit) ----
    const int m  = tid >> 7;
    const int u  = tid & 127;
    const int bm = bid * BQ + m;
    const int sm = m * AST + u;

    // Stage ALL tokens for this WG's 4 samples into LDS (one int4 / thread,
    // coalesced src). Padded stride; zero-fill the 16-entry tail.
    {
        const int4 tv = *(const int4*)(tokens + (size_t)bm * SEQ + (tid & 127) * 4);
        *(int4*)(&tkbuf[m * TKST + (tid & 127) * 4]) = tv;
        if (tid < BQ * 16)
            tkbuf[(tid >> 4) * TKST + SEQ + (tid & 15)] = 0;
    }

    hbuf[sm] = (__bf16)h0[u];
    const int* tokm = tokens + (size_t)bm * SEQ;
#pragma unroll
    for (int k = 0; k < 8; ++k) {   // stage x(0..7) into slots 0..7
        float ek = emb[(size_t)tokm[k] * DIM + u];
        xbuf[k * XST + sm] = (__bf16)fmaxf(ek, 0.0f);
    }
    // gather pipeline, 4 steps deep (one reg per OFF): e(OFF) written at step
    // t (as x(t+8)) then reloaded for step t+4 (as x(t+12)). tk = token for
    // the step-0 reload (x(12)), read one step ahead.
    float e0 = emb[(size_t)tokm[8]  * DIM + u];
    float e1 = emb[(size_t)tokm[9]  * DIM + u];
    float e2 = emb[(size_t)tokm[10] * DIM + u];
    float e3 = emb[(size_t)tokm[11] * DIM + u];
    int   tk = tokm[12];

#define EREG(OFF) ((OFF) == 0 ? e0 : (OFF) == 1 ? e1 : (OFF) == 2 ? e2 : e3)

    // frag pointers
    const int xfbase = (lrow & 3) * XST + (lrow >> 2) * AST + quad * 8;
    const __bf16* const xfp[2] = { &xbuf[xfbase], &xbuf[4 * XST + xfbase] };
    const int habase = (lrow >> 2) * AST + quad * 8;
    const __bf16* const hf[2] = { &hbuf[habase], &hbuf[BQ * AST + habase] };
    __bf16* const hw[2] = { &hbuf[quad * AST + uu], &hbuf[BQ * AST + quad * AST + uu] };
    __bf16* const xw = &xbuf[sm];

    __syncthreads();   // x(0..7), h(0), tokens staged

    const floatx4 zc = {0.0f, 0.0f, 0.0f, 0.0f};   // zero C-init

    // XG[gt][r] = x(ts'+r)@W_ih^T (no bias) for (sample quad, unit uu).
    // xga for superstep 0 built in full here (from slots 0..3); thereafter
    // XGN accumulates one kt-slice per step inside STEP.
    floatx4 xga[4], xgb[4];
    {
        bf16x8 af_[4];
#pragma unroll
        for (int kt = 0; kt < 4; ++kt)
            af_[kt] = *(const bf16x8*)(xfp[0] + kt * 32);
#pragma unroll
        for (int gt = 0; gt < 4; ++gt)
            xga[gt] = __builtin_amdgcn_mfma_f32_16x16x32_bf16(af_[0], wfx[gt][0], zc, 0, 0, 0);
#pragma unroll
        for (int kt = 1; kt < 4; ++kt)
#pragma unroll
            for (int gt = 0; gt < 4; ++gt)
                xga[gt] = __builtin_amdgcn_mfma_f32_16x16x32_bf16(af_[kt], wfx[gt][kt], xga[gt], 0, 0, 0);
    }
    block_sync_lds();    // slots 0..3 rewritten starting at step 0 (x(8))

    bf16x8 axp = {};     // pre-loaded x-slice frag for the NEXT step (OFF+1)

    // G, OFF literals. Per-step order:
    //   post-barrier: 4 h-frag reads (head of the in-order LDS queue);
    //   ax_ = axp (in-register, OFF>0) or fresh load (OFF==0);
    //   staging: x-write (old EREG), gather issue (old tk), THEN the tk
    //   reload and next-step axp load -- their ~120cy latency is absorbed
    //   under the MFMA+activation phase instead of the barrier drain (R11);
    //   x-slice MFMAs first for OFF>0 (operands ready -> issue in h-wait),
    //   split-K h-MFMA (2x2-deep, C=XGC, XGC preserved since D!=C);
    //   re-associated activations; h-write; lgkmcnt(0) drain (h-write only
    //   still outstanding) + barrier.
#define STEP(G, OFF, XGC, XGN) do {                                                  \
        const int t  = ts + OFF;                                                     \
        bf16x8 ah0 = *(const bf16x8*)(hf[OFF & 1] + 0 * 32);                         \
        bf16x8 ah2 = *(const bf16x8*)(hf[OFF & 1] + 2 * 32);                         \
        bf16x8 ah1 = *(const bf16x8*)(hf[OFF & 1] + 1 * 32);                         \
        bf16x8 ah3 = *(const bf16x8*)(hf[OFF & 1] + 3 * 32);                         \
        bf16x8 ax_;                                                                  \
        if ((OFF) == 0) ax_ = *(const bf16x8*)(xfp[1 - (G)] + 0 * 32);               \
        else            ax_ = axp;                                                   \
        if (t + 8 < SEQ)   /* stage x(t+8) from the reg gathered 4 steps ago */      \
            xw[(4 * (G) + (OFF)) * XST] = (__bf16)fmaxf(EREG(OFF), 0.0f);            \
        if (t + 12 < SEQ)  /* gather for x(t+12), uses OLD tk */                     \
            EREG(OFF) = emb[(size_t)tk * DIM + u];                                   \
        tk = tkbuf[m * TKST + t + 13];       /* reload early: latency absorbed */    \
        if ((OFF) < 3)     /* next step's x-slice, early for the same reason */      \
            axp = *(const bf16x8*)(xfp[1 - (G)] + ((OFF) + 1) * 32);                 \
        floatx4 aL[4], aH[4];                                                        \
        if ((OFF) != 0) {  /* x-MFMAs first: operands ready, fill h-read wait */     \
            _Pragma("unroll") for (int gt = 0; gt < 4; ++gt)                         \
                XGN[gt] = __builtin_amdgcn_mfma_f32_16x16x32_bf16(ax_, wfx[gt][OFF], XGN[gt], 0, 0, 0); \
        }                                                                            \
        _Pragma("unroll") for (int gt = 0; gt < 4; ++gt)                             \
            aL[gt] = __builtin_amdgcn_mfma_f32_16x16x32_bf16(ah0, wfh[gt][0], XGC[gt], 0, 0, 0); \
        _Pragma("unroll") for (int gt = 0; gt < 4; ++gt)                             \
            aH[gt] = __builtin_amdgcn_mfma_f32_16x16x32_bf16(ah2, wfh[gt][2], zc, 0, 0, 0); \
        _Pragma("unroll") for (int gt = 0; gt < 4; ++gt)                             \
            aL[gt] = __builtin_amdgcn_mfma_f32_16x16x32_bf16(ah1, wfh[gt][1], aL[gt], 0, 0, 0); \
        _Pragma("unroll") for (int gt = 0; gt < 4; ++gt)                             \
            aH[gt] = __builtin_amdgcn_mfma_f32_16x16x32_bf16(ah3, wfh[gt][3], aH[gt], 0, 0, 0); \
        if ((OFF) == 0) {  /* ax_ loaded post-barrier: issue after h-MFMAs */        \
            _Pragma("unroll") for (int gt = 0; gt < 4; ++gt)                         \
                XGN[gt] = __builtin_amdgcn_mfma_f32_16x16x32_bf16(ax_, wfx[gt][0], zc, 0, 0, 0); \
        }                                                                            \
        const float ii = gate_s(aL[0][OFF], aH[0][OFF], karg0);                      \
        const float ff = gate_s(aL[1][OFF], aH[1][OFF], karg1);                      \
        const float oo = gate_s(aL[3][OFF], aH[3][OFF], karg3);                      \
        const float rg = __builtin_amdgcn_rcpf(1.0f + __builtin_amdgcn_exp2f(       \
            __builtin_fmaf(kT, aL[2][OFF], __builtin_fmaf(kT, aH[2][OFF], karg2)))); \
        const float ig = __builtin_fmaf(2.0f * ii, rg, -ii);  /* i*tanh(g) */        \
        c = __builtin_fmaf(ff, c, ig);                                               \
        const float rc = __builtin_amdgcn_rcpf(1.0f + __builtin_amdgcn_exp2f(kT * c)); \
        const float h = __builtin_fmaf(2.0f * oo, rc, -oo);   /* o*tanh(c) */        \
        if (t == tlast) hl = fmaxf(h, 0.0f);                                         \
        *hw[1 - (OFF & 1)] = (__bf16)h;                                              \
        block_sync_lds();                                                            \
    } while (0)

    for (int ts8 = 0; ts8 < Lmax; ts8 += 8) {
        {
            const int ts = ts8;
            STEP(0, 0, xga, xgb); STEP(0, 1, xga, xgb);
            STEP(0, 2, xga, xgb); STEP(0, 3, xga, xgb);
        }
        {
            const int ts = ts8 + 4;
            STEP(1, 0, xgb, xga); STEP(1, 1, xgb, xga);
            STEP(1, 2, xgb, xga); STEP(1, 3, xgb, xga);
        }
    }
#undef STEP
#undef EREG

    // ---- epilogue: out[b] = [relu(h_last) | onehot] @ linW^T + linb ----
    hlbuf[quad * HID + uu] = hl;
    __syncthreads();
    if (tid < 2 * BQ) {
        const int mm = tid >> 1, kk = tid & 1;
        const int bb = bid * BQ + mm;
        float a2 = linb[kk];
        for (int q = 0; q < HID; ++q)
            a2 += hlbuf[mm * HID + q] * linW[kk * FEAT + q];
        for (int o = 0; o < NOPS; ++o)
            a2 += onehot[bb * NOPS + o] * linW[kk * FEAT + HID + o];
        out[bb * 2 + kk] = a2;
    }
}

extern "C" void kernel_launch(void* const* d_in, const int* in_sizes, int n_in,
                              void* d_out, int out_size, void* d_ws, size_t ws_size,
                              hipStream_t stream) {
    const int*   tokens  = (const int*)d_in[0];
    const int*   lengths = (const int*)d_in[1];
    const float* onehot  = (const float*)d_in[2];
    const float* emb     = (const float*)d_in[3];
    const float* Wih     = (const float*)d_in[4];
    const float* Whh     = (const float*)d_in[5];
    const float* bih     = (const float*)d_in[6];
    const float* bhh     = (const float*)d_in[7];
    const float* h0      = (const float*)d_in[8];
    const float* c0      = (const float*)d_in[9];
    const float* linW    = (const float*)d_in[10];
    const float* linb    = (const float*)d_in[11];
    float* out = (float*)d_out;
    (void)in_sizes; (void)n_in; (void)out_size; (void)d_ws; (void)ws_size;

    lstm_fused<<<dim3(NB / BQ), dim3(512), 0, stream>>>(
        tokens, lengths, onehot, emb, Wih, Whh, bih, bhh, h0, c0, linW, linb, out);
}